// Round 1
// baseline (105063.525 us; speedup 1.0000x reference)
//
#include <hip/hip_runtime.h>
#include <math.h>

#define T_ 256
#define B_ 128
#define F_ 64
#define H_ 512

__device__ __forceinline__ float sigmoidf_(float x) { return 1.0f / (1.0f + expf(-x)); }

// One LSTM cell phase, fully fused:
//   g[b][r] = dot(W1[r,:], in1[b,:]) + dot(W2[r,:], hin[b,:]) + bih[r] + bhh[r]
//   i,f,g,o gates -> c (in-place, thread-exclusive), hout (separate buffer).
// Each thread computes all 4 gate rows {u, 512+u, 1024+u, 1536+u} for one (b,u).
__global__ __launch_bounds__(256) void lstm_cell_kernel(
    const float* __restrict__ in1, int in1_stride, int K1,
    const float* __restrict__ W1,   // [4H][K1]
    const float* __restrict__ hin,  // [B][H]
    const float* __restrict__ W2,   // [4H][H]
    const float* __restrict__ bih, const float* __restrict__ bhh,
    float* __restrict__ c,          // [B][H] in-place
    float* __restrict__ hout)       // [B][H]
{
    const int u = blockIdx.x * 16 + threadIdx.x;   // hidden unit, < 512
    const int b = blockIdx.y * 16 + threadIdx.y;   // batch, < 128

    float acc0 = 0.f, acc1 = 0.f, acc2 = 0.f, acc3 = 0.f;

    // ---- input contribution: W1 rows, K1 wide ----
    {
        const float4* a4 = reinterpret_cast<const float4*>(in1 + (size_t)b * in1_stride);
        const float4* w0 = reinterpret_cast<const float4*>(W1 + (size_t)(0 * H_ + u) * K1);
        const float4* w1 = reinterpret_cast<const float4*>(W1 + (size_t)(1 * H_ + u) * K1);
        const float4* w2 = reinterpret_cast<const float4*>(W1 + (size_t)(2 * H_ + u) * K1);
        const float4* w3 = reinterpret_cast<const float4*>(W1 + (size_t)(3 * H_ + u) * K1);
        const int n4 = K1 >> 2;
        for (int k = 0; k < n4; ++k) {
            float4 a = a4[k];
            float4 x0 = w0[k], x1 = w1[k], x2 = w2[k], x3 = w3[k];
            acc0 += a.x * x0.x + a.y * x0.y + a.z * x0.z + a.w * x0.w;
            acc1 += a.x * x1.x + a.y * x1.y + a.z * x1.z + a.w * x1.w;
            acc2 += a.x * x2.x + a.y * x2.y + a.z * x2.z + a.w * x2.w;
            acc3 += a.x * x3.x + a.y * x3.y + a.z * x3.z + a.w * x3.w;
        }
    }
    // ---- recurrent contribution: W2 rows, H wide ----
    {
        const float4* a4 = reinterpret_cast<const float4*>(hin + (size_t)b * H_);
        const float4* w0 = reinterpret_cast<const float4*>(W2 + (size_t)(0 * H_ + u) * H_);
        const float4* w1 = reinterpret_cast<const float4*>(W2 + (size_t)(1 * H_ + u) * H_);
        const float4* w2 = reinterpret_cast<const float4*>(W2 + (size_t)(2 * H_ + u) * H_);
        const float4* w3 = reinterpret_cast<const float4*>(W2 + (size_t)(3 * H_ + u) * H_);
        const int n4 = H_ >> 2;
        for (int k = 0; k < n4; ++k) {
            float4 a = a4[k];
            float4 x0 = w0[k], x1 = w1[k], x2 = w2[k], x3 = w3[k];
            acc0 += a.x * x0.x + a.y * x0.y + a.z * x0.z + a.w * x0.w;
            acc1 += a.x * x1.x + a.y * x1.y + a.z * x1.z + a.w * x1.w;
            acc2 += a.x * x2.x + a.y * x2.y + a.z * x2.z + a.w * x2.w;
            acc3 += a.x * x3.x + a.y * x3.y + a.z * x3.z + a.w * x3.w;
        }
    }

    acc0 += bih[0 * H_ + u] + bhh[0 * H_ + u];
    acc1 += bih[1 * H_ + u] + bhh[1 * H_ + u];
    acc2 += bih[2 * H_ + u] + bhh[2 * H_ + u];
    acc3 += bih[3 * H_ + u] + bhh[3 * H_ + u];

    const float ig = sigmoidf_(acc0);
    const float fg = sigmoidf_(acc1);
    const float gg = tanhf(acc2);
    const float og = sigmoidf_(acc3);

    const size_t idx = (size_t)b * H_ + u;
    const float cn = fg * c[idx] + ig * gg;
    c[idx] = cn;
    hout[idx] = og * tanhf(cn);
}

// out_t = h1 @ lin_W.T + lin_b ; writes d_out time-slice (flipped) and the
// decoder feedback buffer xin.
__global__ __launch_bounds__(256) void linear_kernel(
    const float* __restrict__ h1,    // [B][H]
    const float* __restrict__ linW,  // [F][H]
    const float* __restrict__ linb,  // [F]
    float* __restrict__ out_slice,   // d_out + (T-1-t)*F  (indexed + b*T*F + f)
    float* __restrict__ xin)         // [B][F]
{
    const int f = threadIdx.x;                        // < 64
    const int b = blockIdx.x * 4 + threadIdx.y;       // < 128

    const float4* a4 = reinterpret_cast<const float4*>(h1 + (size_t)b * H_);
    const float4* w4 = reinterpret_cast<const float4*>(linW + (size_t)f * H_);
    float acc = 0.f;
    for (int k = 0; k < H_ / 4; ++k) {
        float4 a = a4[k], w = w4[k];
        acc += a.x * w.x + a.y * w.y + a.z * w.z + a.w * w.w;
    }
    acc += linb[f];
    out_slice[(size_t)b * T_ * F_ + f] = acc;
    xin[(size_t)b * F_ + f] = acc;
}

extern "C" void kernel_launch(void* const* d_in, const int* in_sizes, int n_in,
                              void* d_out, int out_size, void* d_ws, size_t ws_size,
                              hipStream_t stream) {
    const float* x      = (const float*)d_in[0];
    const float* eWih0  = (const float*)d_in[1];
    const float* eWhh0  = (const float*)d_in[2];
    const float* ebih0  = (const float*)d_in[3];
    const float* ebhh0  = (const float*)d_in[4];
    const float* eWih1  = (const float*)d_in[5];
    const float* eWhh1  = (const float*)d_in[6];
    const float* ebih1  = (const float*)d_in[7];
    const float* ebhh1  = (const float*)d_in[8];
    const float* dWih0  = (const float*)d_in[9];
    const float* dWhh0  = (const float*)d_in[10];
    const float* dbih0  = (const float*)d_in[11];
    const float* dbhh0  = (const float*)d_in[12];
    const float* dWih1  = (const float*)d_in[13];
    const float* dWhh1  = (const float*)d_in[14];
    const float* dbih1  = (const float*)d_in[15];
    const float* dbhh1  = (const float*)d_in[16];
    const float* linW   = (const float*)d_in[17];
    const float* linb   = (const float*)d_in[18];

    float* out = (float*)d_out;
    float* ws  = (float*)d_ws;

    // workspace layout (floats)
    float* h0buf[2] = { ws,            ws + 65536 };
    float* h1buf[2] = { ws + 131072,   ws + 196608 };
    float* c0  = ws + 262144;
    float* c1  = ws + 327680;
    float* xin = ws + 393216;   // 128*64

    // zero h0(both), h1(both), c0, c1
    hipMemsetAsync(ws, 0, (size_t)393216 * sizeof(float), stream);

    const dim3 blk(16, 16);
    const dim3 grd(H_ / 16, B_ / 16);   // 32 x 8 = 256 WGs

    // ---------------- encoder ----------------
    for (int t = 0; t < T_; ++t) {
        float* h0r = h0buf[t & 1];
        float* h0w = h0buf[(t + 1) & 1];
        float* h1r = h1buf[t & 1];
        float* h1w = h1buf[(t + 1) & 1];
        lstm_cell_kernel<<<grd, blk, 0, stream>>>(
            x + (size_t)t * F_, T_ * F_, F_, eWih0, h0r, eWhh0, ebih0, ebhh0, c0, h0w);
        lstm_cell_kernel<<<grd, blk, 0, stream>>>(
            h0w, H_, H_, eWih1, h1r, eWhh1, ebih1, ebhh1, c1, h1w);
    }

    // ---------------- decoder ----------------
    // after 256 encoder steps the live buffers are index 0; decoder t parity continues.
    for (int t = 0; t < T_; ++t) {
        const float* in1 = (t == 0) ? (x + (size_t)(T_ - 1) * F_) : xin;
        const int in1_stride = (t == 0) ? (T_ * F_) : F_;
        float* h0r = h0buf[t & 1];
        float* h0w = h0buf[(t + 1) & 1];
        float* h1r = h1buf[t & 1];
        float* h1w = h1buf[(t + 1) & 1];
        lstm_cell_kernel<<<grd, blk, 0, stream>>>(
            in1, in1_stride, F_, dWih0, h0r, dWhh0, dbih0, dbhh0, c0, h0w);
        lstm_cell_kernel<<<grd, blk, 0, stream>>>(
            h0w, H_, H_, dWih1, h1r, dWhh1, dbih1, dbhh1, c1, h1w);
        linear_kernel<<<32, dim3(64, 4), 0, stream>>>(
            h1w, linW, linb, out + (size_t)(T_ - 1 - t) * F_, xin);
    }
}

// Round 2
// 61014.795 us; speedup vs baseline: 1.7219x; 1.7219x over previous
//
#include <hip/hip_runtime.h>
#include <math.h>

#define T_ 256
#define B_ 128
#define F_ 64
#define H_ 512
#define NWG 256

// ws layout (float offsets)
#define WS_H0A   0
#define WS_H0B   65536
#define WS_H1A   131072
#define WS_H1B   196608
#define WS_C0    262144
#define WS_C1    327680
#define WS_XIN0  393216     // 128*2048
#define WS_BIAS  655360     // 5 * 2048: e0, e1, d0, d1, beff
#define WS_BAR   665600     // int counter (bytes 2662400)

__device__ __forceinline__ float sigf(float x) { return 1.0f / (1.0f + expf(-x)); }
__device__ __forceinline__ float dot4(float4 a, float4 b) {
    return a.x * b.x + a.y * b.y + a.z * b.z + a.w * b.w;
}

// monotonic-counter grid barrier (device scope, XCD-safe)
__device__ __forceinline__ void gbar(int* cnt, int g) {
    __syncthreads();
    if (threadIdx.x == 0) {
        __threadfence();  // release prior writes device-wide
        __hip_atomic_fetch_add(cnt, 1, __ATOMIC_ACQ_REL, __HIP_MEMORY_SCOPE_AGENT);
        while (__hip_atomic_load(cnt, __ATOMIC_RELAXED, __HIP_MEMORY_SCOPE_AGENT) < g * NWG) {
            __builtin_amdgcn_s_sleep(2);
        }
        __threadfence();  // acquire
    }
    __syncthreads();
}

__global__ __launch_bounds__(256, 1) void lstm_persist(
    const float* __restrict__ x,
    const float* __restrict__ eWih0, const float* __restrict__ eWhh0,
    const float* __restrict__ ebih0, const float* __restrict__ ebhh0,
    const float* __restrict__ eWih1, const float* __restrict__ eWhh1,
    const float* __restrict__ ebih1, const float* __restrict__ ebhh1,
    const float* __restrict__ dWih0, const float* __restrict__ dWhh0,
    const float* __restrict__ dbih0, const float* __restrict__ dbhh0,
    const float* __restrict__ dWih1, const float* __restrict__ dWhh1,
    const float* __restrict__ dbih1, const float* __restrict__ dbhh1,
    const float* __restrict__ linW,  const float* __restrict__ linb,
    float* __restrict__ out, float* __restrict__ ws, int* __restrict__ bar)
{
    const int w    = blockIdx.x;
    const int tid  = threadIdx.x;
    const int wave = tid >> 6;
    const int lane = tid & 63;

    __shared__ float wlds[16384];   // 64 KB

    float* h0buf[2] = { ws + WS_H0A, ws + WS_H0B };
    float* h1buf[2] = { ws + WS_H1A, ws + WS_H1B };
    float* c0   = ws + WS_C0;
    float* c1   = ws + WS_C1;
    float* xin0 = ws + WS_XIN0;
    float* bias_e0 = ws + WS_BIAS;
    float* bias_e1 = bias_e0 + 2048;
    float* bias_d0 = bias_e0 + 4096;
    float* bias_d1 = bias_e0 + 6144;
    float* beff    = bias_e0 + 8192;

    int g = 0;  // barrier generation

    // ================= INIT =================
    // zero h0[2], h1[2], c0, c1  (393216 floats, 6 per thread)
    for (int i = w * 256 + tid; i < 393216; i += NWG * 256) ws[i] = 0.0f;

    // biases: 5 arrays x 2048, 32 WGs per array, 64 entries per WG
    if (w < 160 && tid < 64) {
        const int arr = w >> 5;
        const int r = ((w & 31) << 6) + tid;
        float v;
        if (arr == 0)      v = ebih0[r] + ebhh0[r];
        else if (arr == 1) v = ebih1[r] + ebhh1[r];
        else if (arr == 2) v = dbih0[r] + dbhh0[r];
        else if (arr == 3) v = dbih1[r] + dbhh1[r];
        else { float s = 0.f; for (int f2 = 0; f2 < 64; ++f2) s += dWih0[(size_t)r * 64 + f2] * linb[f2]; v = s; }
        bias_e0[arr * 2048 + r] = v;
    }

    // xin0_proj[b][r] = dot(dWih0[r], x[b][T-1]); WG handles rows [8w, 8w+8)
    for (int idx = tid; idx < 1024; idx += 256) {
        const int rr = idx >> 7, b = idx & 127;
        const int r = w * 8 + rr;
        const float* xr = x + ((size_t)b * T_ + (T_ - 1)) * F_;
        const float* wr = dWih0 + (size_t)r * 64;
        float s = 0.f;
        for (int f2 = 0; f2 < 64; ++f2) s += wr[f2] * xr[f2];
        xin0[(size_t)b * 2048 + r] = s;
    }

    // encoder weights -> LDS
    if (w < 128) {                 // cellA slice: 16 rows x 576 ([Wih0|Whh0])
        for (int rr = 0; rr < 16; ++rr) {
            const int uu = rr >> 2, gg = rr & 3;
            const int r = gg * H_ + (w * 4 + uu);
            float* dst = wlds + rr * 576;
            if (tid < 64) dst[tid] = eWih0[(size_t)r * 64 + tid];
            for (int k = tid; k < 512; k += 256) dst[64 + k] = eWhh0[(size_t)r * H_ + k];
        }
    } else {                       // cellB slice: 16 rows x 1024 ([Wih1|Whh1])
        for (int rr = 0; rr < 16; ++rr) {
            const int uu = rr >> 2, gg = rr & 3;
            const int r = gg * H_ + ((w - 128) * 4 + uu);
            float* dst = wlds + rr * 1024;
            for (int k = tid; k < 512; k += 256) {
                dst[k]       = eWih1[(size_t)r * H_ + k];
                dst[512 + k] = eWhh1[(size_t)r * H_ + k];
            }
        }
    }
    gbar(bar, ++g);

    // ================= ENCODER: 257 pipelined phases =================
    for (int p = 0; p <= T_; ++p) {
        if (w < 128) {
            if (p < T_) {   // cellA(t=p): 4u, wave=u, 2 b/lane
                const int t = p;
                const int uu = wave;
                const int u = (w << 2) + uu;
                const float* wbase = wlds + (uu * 4) * 576;
                const int b0 = lane, b1 = lane + 64;
                float acc0[4] = {0, 0, 0, 0}, acc1[4] = {0, 0, 0, 0};
                {   // x segment (K=64)
                    const float4* a0 = (const float4*)(x + ((size_t)b0 * T_ + t) * F_);
                    const float4* a1 = (const float4*)(x + ((size_t)b1 * T_ + t) * F_);
                    #pragma unroll
                    for (int k = 0; k < 16; ++k) {
                        float4 v0 = a0[k], v1 = a1[k];
                        #pragma unroll
                        for (int gg = 0; gg < 4; ++gg) {
                            float4 wv = ((const float4*)(wbase + gg * 576))[k];
                            acc0[gg] += dot4(v0, wv);
                            acc1[gg] += dot4(v1, wv);
                        }
                    }
                }
                {   // h segment (K=512)
                    const float* hr = h0buf[(t + 1) & 1];
                    const float4* a0 = (const float4*)(hr + (size_t)b0 * H_);
                    const float4* a1 = (const float4*)(hr + (size_t)b1 * H_);
                    #pragma unroll 8
                    for (int k = 0; k < 128; ++k) {
                        float4 v0 = a0[k], v1 = a1[k];
                        #pragma unroll
                        for (int gg = 0; gg < 4; ++gg) {
                            float4 wv = ((const float4*)(wbase + gg * 576 + 64))[k];
                            acc0[gg] += dot4(v0, wv);
                            acc1[gg] += dot4(v1, wv);
                        }
                    }
                }
                float bz[4];
                #pragma unroll
                for (int gg = 0; gg < 4; ++gg) bz[gg] = bias_e0[gg * H_ + u];
                float* hw = h0buf[t & 1];
                {
                    float gi = sigf(acc0[0] + bz[0]), gf = sigf(acc0[1] + bz[1]);
                    float gt = tanhf(acc0[2] + bz[2]), go = sigf(acc0[3] + bz[3]);
                    const size_t idx = (size_t)b0 * H_ + u;
                    float cn = gf * c0[idx] + gi * gt;
                    c0[idx] = cn; hw[idx] = go * tanhf(cn);
                }
                {
                    float gi = sigf(acc1[0] + bz[0]), gf = sigf(acc1[1] + bz[1]);
                    float gt = tanhf(acc1[2] + bz[2]), go = sigf(acc1[3] + bz[3]);
                    const size_t idx = (size_t)b1 * H_ + u;
                    float cn = gf * c0[idx] + gi * gt;
                    c0[idx] = cn; hw[idx] = go * tanhf(cn);
                }
            }
        } else {
            if (p >= 1) {   // cellB(t=p-1)
                const int t = p - 1;
                const int uu = wave;
                const int u = ((w - 128) << 2) + uu;
                const float* wbase = wlds + (uu * 4) * 1024;
                const int b0 = lane, b1 = lane + 64;
                float acc0[4] = {0, 0, 0, 0}, acc1[4] = {0, 0, 0, 0};
                {   // input segment: h0_t
                    const float* hr = h0buf[t & 1];
                    const float4* a0 = (const float4*)(hr + (size_t)b0 * H_);
                    const float4* a1 = (const float4*)(hr + (size_t)b1 * H_);
                    #pragma unroll 8
                    for (int k = 0; k < 128; ++k) {
                        float4 v0 = a0[k], v1 = a1[k];
                        #pragma unroll
                        for (int gg = 0; gg < 4; ++gg) {
                            float4 wv = ((const float4*)(wbase + gg * 1024))[k];
                            acc0[gg] += dot4(v0, wv);
                            acc1[gg] += dot4(v1, wv);
                        }
                    }
                }
                {   // recurrent segment: h1_{t-1}
                    const float* hr = h1buf[(t + 1) & 1];
                    const float4* a0 = (const float4*)(hr + (size_t)b0 * H_);
                    const float4* a1 = (const float4*)(hr + (size_t)b1 * H_);
                    #pragma unroll 8
                    for (int k = 0; k < 128; ++k) {
                        float4 v0 = a0[k], v1 = a1[k];
                        #pragma unroll
                        for (int gg = 0; gg < 4; ++gg) {
                            float4 wv = ((const float4*)(wbase + gg * 1024 + 512))[k];
                            acc0[gg] += dot4(v0, wv);
                            acc1[gg] += dot4(v1, wv);
                        }
                    }
                }
                float bz[4];
                #pragma unroll
                for (int gg = 0; gg < 4; ++gg) bz[gg] = bias_e1[gg * H_ + u];
                float* hw = h1buf[t & 1];
                {
                    float gi = sigf(acc0[0] + bz[0]), gf = sigf(acc0[1] + bz[1]);
                    float gt = tanhf(acc0[2] + bz[2]), go = sigf(acc0[3] + bz[3]);
                    const size_t idx = (size_t)b0 * H_ + u;
                    float cn = gf * c1[idx] + gi * gt;
                    c1[idx] = cn; hw[idx] = go * tanhf(cn);
                }
                {
                    float gi = sigf(acc1[0] + bz[0]), gf = sigf(acc1[1] + bz[1]);
                    float gt = tanhf(acc1[2] + bz[2]), go = sigf(acc1[3] + bz[3]);
                    const size_t idx = (size_t)b1 * H_ + u;
                    float cn = gf * c1[idx] + gi * gt;
                    c1[idx] = cn; hw[idx] = go * tanhf(cn);
                }
            }
        }
        gbar(bar, ++g);
    }

    // ================= TRANSITION: decoder weights -> LDS =================
    // dec0 slice rows 0..7: [Weff (computed) | dWhh0]; dec1 slice rows 8..15: [dWih1 | dWhh1]
    for (int rr = 0; rr < 8; ++rr) {
        const int uu = rr >> 2, gg = rr & 3;
        const int r = gg * H_ + ((w << 1) + uu);
        float* dst = wlds + rr * 1024;
        const float* wr = dWih0 + (size_t)r * 64;
        for (int c = tid; c < 512; c += 256) {
            float s = 0.f;
            for (int f2 = 0; f2 < 64; ++f2) s += wr[f2] * linW[(size_t)f2 * H_ + c];
            dst[c] = s;
            dst[512 + c] = dWhh0[(size_t)r * H_ + c];
        }
        float* dst1 = wlds + 8192 + rr * 1024;
        for (int c = tid; c < 512; c += 256) {
            dst1[c]       = dWih1[(size_t)r * H_ + c];
            dst1[512 + c] = dWhh1[(size_t)r * H_ + c];
        }
    }
    gbar(bar, ++g);

    // ================= DECODER: 512 phases =================
    for (int t = 0; t < T_; ++t) {
        {   // ---- cellA = dec0(t), all 256 WGs, 2u ----
            const int uu = wave & 1;
            const int bh = wave >> 1;
            const int u = (w << 1) + uu;
            const int b = (bh << 6) + lane;
            const float* wbase = wlds + (uu * 4) * 1024;
            float acc[4];
            if (t > 0) {   // Weff . h1_{t-1}
                #pragma unroll
                for (int gg = 0; gg < 4; ++gg) acc[gg] = 0.f;
                const float4* a = (const float4*)(h1buf[(t + 1) & 1] + (size_t)b * H_);
                #pragma unroll 8
                for (int k = 0; k < 128; ++k) {
                    float4 v = a[k];
                    #pragma unroll
                    for (int gg = 0; gg < 4; ++gg)
                        acc[gg] += dot4(v, ((const float4*)(wbase + gg * 1024))[k]);
                }
            } else {       // precomputed x_last projection
                #pragma unroll
                for (int gg = 0; gg < 4; ++gg) acc[gg] = xin0[(size_t)b * 2048 + gg * H_ + u];
            }
            {   // dWhh0 . h0_{t-1}
                const float4* a = (const float4*)(h0buf[(t + 1) & 1] + (size_t)b * H_);
                #pragma unroll 8
                for (int k = 0; k < 128; ++k) {
                    float4 v = a[k];
                    #pragma unroll
                    for (int gg = 0; gg < 4; ++gg)
                        acc[gg] += dot4(v, ((const float4*)(wbase + gg * 1024 + 512))[k]);
                }
            }
            float bz[4];
            #pragma unroll
            for (int gg = 0; gg < 4; ++gg) {
                bz[gg] = bias_d0[gg * H_ + u];
                if (t > 0) bz[gg] += beff[gg * H_ + u];
            }
            float gi = sigf(acc[0] + bz[0]), gf = sigf(acc[1] + bz[1]);
            float gt = tanhf(acc[2] + bz[2]), go = sigf(acc[3] + bz[3]);
            const size_t idx = (size_t)b * H_ + u;
            float cn = gf * c0[idx] + gi * gt;
            c0[idx] = cn;
            h0buf[t & 1][idx] = go * tanhf(cn);

            if (t > 0) {   // ---- folded linear(t-1) ----
                const int bl = w >> 1;
                const int fh = w & 1;
                const int kq = tid & 7;
                const int fi = tid >> 3;
                const int f = (fh << 5) + fi;
                const float* hrow = h1buf[(t + 1) & 1] + (size_t)bl * H_;
                const float4* hv = (const float4*)(hrow + (kq << 6));
                const float4* wv = (const float4*)(linW + (size_t)f * H_ + (kq << 6));
                float s = 0.f;
                #pragma unroll
                for (int i = 0; i < 16; ++i) s += dot4(hv[i], wv[i]);
                s += __shfl_xor(s, 1);
                s += __shfl_xor(s, 2);
                s += __shfl_xor(s, 4);
                if (kq == 0)
                    out[((size_t)bl * T_ + (T_ - 1 - (t - 1))) * F_ + f] = s + linb[f];
            }
        }
        gbar(bar, ++g);

        {   // ---- cellB = dec1(t), all 256 WGs, 2u ----
            const int uu = wave & 1;
            const int bh = wave >> 1;
            const int u = (w << 1) + uu;
            const int b = (bh << 6) + lane;
            const float* wbase = wlds + 8192 + (uu * 4) * 1024;
            float acc[4] = {0, 0, 0, 0};
            {   // dWih1 . h0_t
                const float4* a = (const float4*)(h0buf[t & 1] + (size_t)b * H_);
                #pragma unroll 8
                for (int k = 0; k < 128; ++k) {
                    float4 v = a[k];
                    #pragma unroll
                    for (int gg = 0; gg < 4; ++gg)
                        acc[gg] += dot4(v, ((const float4*)(wbase + gg * 1024))[k]);
                }
            }
            {   // dWhh1 . h1_{t-1}
                const float4* a = (const float4*)(h1buf[(t + 1) & 1] + (size_t)b * H_);
                #pragma unroll 8
                for (int k = 0; k < 128; ++k) {
                    float4 v = a[k];
                    #pragma unroll
                    for (int gg = 0; gg < 4; ++gg)
                        acc[gg] += dot4(v, ((const float4*)(wbase + gg * 1024 + 512))[k]);
                }
            }
            float gi = sigf(acc[0] + bias_d1[0 * H_ + u]), gf = sigf(acc[1] + bias_d1[1 * H_ + u]);
            float gt = tanhf(acc[2] + bias_d1[2 * H_ + u]), go = sigf(acc[3] + bias_d1[3 * H_ + u]);
            const size_t idx = (size_t)b * H_ + u;
            float cn = gf * c1[idx] + gi * gt;
            c1[idx] = cn;
            h1buf[t & 1][idx] = go * tanhf(cn);
        }
        gbar(bar, ++g);
    }

    // ---- final linear(t=255) ----
    {
        const int bl = w >> 1;
        const int fh = w & 1;
        const int kq = tid & 7;
        const int fi = tid >> 3;
        const int f = (fh << 5) + fi;
        const float* hrow = h1buf[1] + (size_t)bl * H_;   // h1_{255} in buf[255&1]
        const float4* hv = (const float4*)(hrow + (kq << 6));
        const float4* wv = (const float4*)(linW + (size_t)f * H_ + (kq << 6));
        float s = 0.f;
        #pragma unroll
        for (int i = 0; i < 16; ++i) s += dot4(hv[i], wv[i]);
        s += __shfl_xor(s, 1);
        s += __shfl_xor(s, 2);
        s += __shfl_xor(s, 4);
        if (kq == 0)
            out[((size_t)bl * T_ + 0) * F_ + f] = s + linb[f];
    }
}

extern "C" void kernel_launch(void* const* d_in, const int* in_sizes, int n_in,
                              void* d_out, int out_size, void* d_ws, size_t ws_size,
                              hipStream_t stream) {
    const float* x     = (const float*)d_in[0];
    const float* eWih0 = (const float*)d_in[1];
    const float* eWhh0 = (const float*)d_in[2];
    const float* ebih0 = (const float*)d_in[3];
    const float* ebhh0 = (const float*)d_in[4];
    const float* eWih1 = (const float*)d_in[5];
    const float* eWhh1 = (const float*)d_in[6];
    const float* ebih1 = (const float*)d_in[7];
    const float* ebhh1 = (const float*)d_in[8];
    const float* dWih0 = (const float*)d_in[9];
    const float* dWhh0 = (const float*)d_in[10];
    const float* dbih0 = (const float*)d_in[11];
    const float* dbhh0 = (const float*)d_in[12];
    const float* dWih1 = (const float*)d_in[13];
    const float* dWhh1 = (const float*)d_in[14];
    const float* dbih1 = (const float*)d_in[15];
    const float* dbhh1 = (const float*)d_in[16];
    const float* linW  = (const float*)d_in[17];
    const float* linb  = (const float*)d_in[18];

    float* ws = (float*)d_ws;
    int* bar = (int*)(ws + WS_BAR);

    hipMemsetAsync(bar, 0, 16, stream);

    hipLaunchKernelGGL(lstm_persist, dim3(NWG), dim3(256), 0, stream,
                       x, eWih0, eWhh0, ebih0, ebhh0, eWih1, eWhh1, ebih1, ebhh1,
                       dWih0, dWhh0, dbih0, dbhh0, dWih1, dWhh1, dbih1, dbhh1,
                       linW, linb, (float*)d_out, ws, bar);
}

// Round 3
// 49760.550 us; speedup vs baseline: 2.1114x; 1.2262x over previous
//
#include <hip/hip_runtime.h>
#include <math.h>

#define T_ 256
#define B_ 128
#define F_ 64
#define H_ 512
#define NWG 256

// ws layout (float offsets). All state transposed: [u][b], b contiguous.
#define WS_H0A   0
#define WS_H0B   65536
#define WS_H1A   131072
#define WS_H1B   196608
#define WS_C0    262144
#define WS_C1    327680
#define WS_XIN0  393216     // [2048 r][128 b]
#define WS_BIAS  655360     // 5 * 2048: e0, e1, d0, d1, beff
#define WS_LINWT 665600     // linWT[512 u][64 f]
#define WS_BAR   698368     // barrier ints: 8 groups *32 + root

__device__ __forceinline__ float sigf(float x) { return 1.0f / (1.0f + expf(-x)); }

// 8-group tree barrier, monotonic generations (reset by memset before launch).
__device__ __forceinline__ void gbar(int* bar, int w, int gen) {
    __syncthreads();
    if (threadIdx.x == 0) {
        int* grp  = bar + (w & 7) * 32;
        int* root = bar + 256;
        int old = __hip_atomic_fetch_add(grp, 1, __ATOMIC_ACQ_REL, __HIP_MEMORY_SCOPE_AGENT);
        if (old == gen * 32 - 1)
            __hip_atomic_fetch_add(root, 1, __ATOMIC_ACQ_REL, __HIP_MEMORY_SCOPE_AGENT);
        while (__hip_atomic_load(root, __ATOMIC_ACQUIRE, __HIP_MEMORY_SCOPE_AGENT) < gen * 8)
            __builtin_amdgcn_s_sleep(1);
    }
    __syncthreads();
}

// 4-gate dot segment: weights from LDS (wave-uniform b128 broadcast),
// activations from global [k][128] layout, coalesced 256B per load.
template<int KROW>
__device__ __forceinline__ void dotseg(const float* wl, const float* act_b, int kseg, float acc[4]) {
    #pragma unroll 4
    for (int k = 0; k < kseg; k += 4) {
        float4 w0 = *(const float4*)(wl + 0 * KROW + k);
        float4 w1 = *(const float4*)(wl + 1 * KROW + k);
        float4 w2 = *(const float4*)(wl + 2 * KROW + k);
        float4 w3 = *(const float4*)(wl + 3 * KROW + k);
        float a0 = act_b[(k + 0) * 128];
        float a1 = act_b[(k + 1) * 128];
        float a2 = act_b[(k + 2) * 128];
        float a3 = act_b[(k + 3) * 128];
        acc[0] += w0.x * a0; acc[1] += w1.x * a0; acc[2] += w2.x * a0; acc[3] += w3.x * a0;
        acc[0] += w0.y * a1; acc[1] += w1.y * a1; acc[2] += w2.y * a1; acc[3] += w3.y * a1;
        acc[0] += w0.z * a2; acc[1] += w1.z * a2; acc[2] += w2.z * a2; acc[3] += w3.z * a2;
        acc[0] += w0.w * a3; acc[1] += w1.w * a3; acc[2] += w2.w * a3; acc[3] += w3.w * a3;
    }
}

__device__ __forceinline__ void gates_store(const float acc[4], const float* bias, int u, int b,
                                            float* cT, float* hT) {
    float gi = sigf(acc[0] + bias[0 * H_ + u]);
    float gf = sigf(acc[1] + bias[1 * H_ + u]);
    float gt = tanhf(acc[2] + bias[2 * H_ + u]);
    float go = sigf(acc[3] + bias[3 * H_ + u]);
    const int idx = u * 128 + b;
    float cn = gf * cT[idx] + gi * gt;
    cT[idx] = cn;
    hT[idx] = go * tanhf(cn);
}

__device__ __forceinline__ void linear_out(const float* h1, const float* linWT, const float* linb,
                                           float* out, int w, int tid, int t) {
    const int bl = w >> 1;
    const int fh = w & 1;
    const int kq = tid & 7;
    const int fi = tid >> 3;       // 0..31
    const int f = fh * 32 + fi;
    float s = 0.f;
    #pragma unroll 8
    for (int i = 0; i < 64; ++i) {
        int uu = kq * 64 + i;
        s += h1[uu * 128 + bl] * linWT[uu * 64 + f];
    }
    s += __shfl_xor(s, 1);
    s += __shfl_xor(s, 2);
    s += __shfl_xor(s, 4);
    if (kq == 0)
        out[(size_t)bl * (T_ * F_) + (255 - t) * 64 + f] = s + linb[f];
}

__global__ __launch_bounds__(256, 1) void lstm_persist(
    const float* __restrict__ x,
    const float* __restrict__ eWih0, const float* __restrict__ eWhh0,
    const float* __restrict__ ebih0, const float* __restrict__ ebhh0,
    const float* __restrict__ eWih1, const float* __restrict__ eWhh1,
    const float* __restrict__ ebih1, const float* __restrict__ ebhh1,
    const float* __restrict__ dWih0, const float* __restrict__ dWhh0,
    const float* __restrict__ dbih0, const float* __restrict__ dbhh0,
    const float* __restrict__ dWih1, const float* __restrict__ dWhh1,
    const float* __restrict__ dbih1, const float* __restrict__ dbhh1,
    const float* __restrict__ linW,  const float* __restrict__ linb,
    float* __restrict__ out, float* __restrict__ ws, int* __restrict__ bar)
{
    const int w    = blockIdx.x;
    const int tid  = threadIdx.x;
    const int wave = tid >> 6;
    const int lane = tid & 63;
    const int u_loc = wave >> 1;      // 0..1
    const int bh    = wave & 1;       // 0..1
    const int u = w * 2 + u_loc;      // 0..511
    const int b = bh * 64 + lane;     // 0..127

    __shared__ float wlds[16384];     // 64 KB

    float* h0buf[2] = { ws + WS_H0A, ws + WS_H0B };
    float* h1buf[2] = { ws + WS_H1A, ws + WS_H1B };
    float* c0T   = ws + WS_C0;
    float* c1T   = ws + WS_C1;
    float* xin0T = ws + WS_XIN0;
    float* bias_e0 = ws + WS_BIAS;
    float* bias_e1 = bias_e0 + 2048;
    float* bias_d0 = bias_e0 + 4096;
    float* bias_d1 = bias_e0 + 6144;
    float* beff    = bias_e0 + 8192;
    float* linWT   = ws + WS_LINWT;

    int gen = 0;

    // ================= INIT =================
    {   // zero h0T[1], h1T[1], c0T, c1T (each 65536 floats, 1 per thread per array)
        const int i = w * 256 + tid;
        h0buf[1][i] = 0.f; h1buf[1][i] = 0.f; c0T[i] = 0.f; c1T[i] = 0.f;
    }
    // combined biases (+ beff)
    if (w < 160 && tid < 64) {
        const int arr = w >> 5;
        const int r = ((w & 31) << 6) + tid;
        float v;
        if (arr == 0)      v = ebih0[r] + ebhh0[r];
        else if (arr == 1) v = ebih1[r] + ebhh1[r];
        else if (arr == 2) v = dbih0[r] + dbhh0[r];
        else if (arr == 3) v = dbih1[r] + dbhh1[r];
        else { float s = 0.f; for (int f2 = 0; f2 < 64; ++f2) s += dWih0[(size_t)r * 64 + f2] * linb[f2]; v = s; }
        bias_e0[arr * 2048 + r] = v;
    }
    // linWT[u][f] = linW[f][u]
    if (tid < 128) {
        const int i = w * 128 + tid;
        linWT[i] = linW[(size_t)(i & 63) * H_ + (i >> 6)];
    }
    // xin0T[r][b] = dot(dWih0[r], x[b][255][:])
    {
        const int b2 = tid & 127;
        const int rr = tid >> 7;     // 0..1
        const float* xr = x + ((size_t)b2 * T_ + (T_ - 1)) * F_;
        for (int j = 0; j < 4; ++j) {
            const int r = w * 8 + rr * 4 + j;
            const float* wr = dWih0 + (size_t)r * 64;
            float s = 0.f;
            for (int f2 = 0; f2 < 64; ++f2) s += wr[f2] * xr[f2];
            xin0T[(size_t)r * 128 + b2] = s;
        }
    }
    // encoder weights -> LDS: cellA [2u][4g][576] at 0, cellB [2u][4g][1024] at 4608
    for (int rr = 0; rr < 8; ++rr) {
        const int up = rr >> 2, gg = rr & 3;
        const int r = gg * H_ + (w * 2 + up);
        float* dstA = wlds + up * 2304 + gg * 576;
        for (int c = tid; c < 576; c += 256)
            dstA[c] = (c < 64) ? eWih0[(size_t)r * 64 + c] : eWhh0[(size_t)r * H_ + (c - 64)];
        float* dstB = wlds + 4608 + up * 4096 + gg * 1024;
        for (int c = tid; c < 1024; c += 256)
            dstB[c] = (c < 512) ? eWih1[(size_t)r * H_ + c] : eWhh1[(size_t)r * H_ + (c - 512)];
    }
    gbar(bar, w, ++gen);

    // ================= ENCODER: 512 serial phases =================
    for (int t = 0; t < T_; ++t) {
        {   // cellA(t): x-seg (direct, K=64) + h0 recurrent
            float acc[4] = {0, 0, 0, 0};
            const float* wl = wlds + u_loc * 2304;
            const float* xa = x + ((size_t)b * T_ + t) * F_;
            #pragma unroll
            for (int k = 0; k < 64; k += 4) {
                float4 w0 = *(const float4*)(wl + 0 * 576 + k);
                float4 w1 = *(const float4*)(wl + 1 * 576 + k);
                float4 w2 = *(const float4*)(wl + 2 * 576 + k);
                float4 w3 = *(const float4*)(wl + 3 * 576 + k);
                float4 a = *(const float4*)(xa + k);
                acc[0] += w0.x * a.x + w0.y * a.y + w0.z * a.z + w0.w * a.w;
                acc[1] += w1.x * a.x + w1.y * a.y + w1.z * a.z + w1.w * a.w;
                acc[2] += w2.x * a.x + w2.y * a.y + w2.z * a.z + w2.w * a.w;
                acc[3] += w3.x * a.x + w3.y * a.y + w3.z * a.z + w3.w * a.w;
            }
            dotseg<576>(wl + 64, h0buf[(t + 1) & 1] + b, 512, acc);
            gates_store(acc, bias_e0, u, b, c0T, h0buf[t & 1]);
        }
        gbar(bar, w, ++gen);

        {   // cellB(t): in = h0_t, rec = h1_{t-1}
            float acc[4] = {0, 0, 0, 0};
            const float* wl = wlds + 4608 + u_loc * 4096;
            dotseg<1024>(wl, h0buf[t & 1] + b, 512, acc);
            dotseg<1024>(wl + 512, h1buf[(t + 1) & 1] + b, 512, acc);
            gates_store(acc, bias_e1, u, b, c1T, h1buf[t & 1]);
        }
        gbar(bar, w, ++gen);
    }

    // ================= TRANSITION: decoder weights -> LDS =================
    // dec0 [2u][4g][ Weff(512) | dWhh0(512) ] at 0; dec1 [2u][4g][ dWih1 | dWhh1 ] at 8192
    for (int rr = 0; rr < 8; ++rr) {
        const int up = rr >> 2, gg = rr & 3;
        const int r = gg * H_ + (w * 2 + up);
        float* dst0 = wlds + up * 4096 + gg * 1024;
        const float* wr = dWih0 + (size_t)r * 64;
        for (int c = tid; c < 512; c += 256) {
            float s = 0.f;
            for (int f2 = 0; f2 < 64; ++f2) s += wr[f2] * linW[(size_t)f2 * H_ + c];
            dst0[c] = s;
            dst0[512 + c] = dWhh0[(size_t)r * H_ + c];
        }
        float* dst1 = wlds + 8192 + up * 4096 + gg * 1024;
        for (int c = tid; c < 512; c += 256) {
            dst1[c]       = dWih1[(size_t)r * H_ + c];
            dst1[512 + c] = dWhh1[(size_t)r * H_ + c];
        }
    }
    gbar(bar, w, ++gen);

    // ================= DECODER: 512 serial phases =================
    for (int t = 0; t < T_; ++t) {
        {   // dec0(t): Weff . h1_{t-1} (or xin0T at t=0) + dWhh0 . h0_{t-1}
            float acc[4] = {0, 0, 0, 0};
            const float* wl = wlds + u_loc * 4096;
            if (t > 0) {
                dotseg<1024>(wl, h1buf[(t + 1) & 1] + b, 512, acc);
                #pragma unroll
                for (int gg = 0; gg < 4; ++gg) acc[gg] += beff[gg * H_ + u];
            } else {
                #pragma unroll
                for (int gg = 0; gg < 4; ++gg) acc[gg] = xin0T[(size_t)(gg * H_ + u) * 128 + b];
            }
            dotseg<1024>(wl + 512, h0buf[(t + 1) & 1] + b, 512, acc);
            gates_store(acc, bias_d0, u, b, c0T, h0buf[t & 1]);

            if (t > 0)   // folded linear(t-1): reads h1_{t-1} = h1buf[(t+1)&1]
                linear_out(h1buf[(t + 1) & 1], linWT, linb, out, w, tid, t - 1);
        }
        gbar(bar, w, ++gen);

        {   // dec1(t): dWih1 . h0_t + dWhh1 . h1_{t-1}
            float acc[4] = {0, 0, 0, 0};
            const float* wl = wlds + 8192 + u_loc * 4096;
            dotseg<1024>(wl, h0buf[t & 1] + b, 512, acc);
            dotseg<1024>(wl + 512, h1buf[(t + 1) & 1] + b, 512, acc);
            gates_store(acc, bias_d1, u, b, c1T, h1buf[t & 1]);
        }
        gbar(bar, w, ++gen);
    }

    // final linear(t=255): h1_255 in h1buf[1]
    linear_out(h1buf[1], linWT, linb, out, w, tid, 255);
}

extern "C" void kernel_launch(void* const* d_in, const int* in_sizes, int n_in,
                              void* d_out, int out_size, void* d_ws, size_t ws_size,
                              hipStream_t stream) {
    const float* x     = (const float*)d_in[0];
    const float* eWih0 = (const float*)d_in[1];
    const float* eWhh0 = (const float*)d_in[2];
    const float* ebih0 = (const float*)d_in[3];
    const float* ebhh0 = (const float*)d_in[4];
    const float* eWih1 = (const float*)d_in[5];
    const float* eWhh1 = (const float*)d_in[6];
    const float* ebih1 = (const float*)d_in[7];
    const float* ebhh1 = (const float*)d_in[8];
    const float* dWih0 = (const float*)d_in[9];
    const float* dWhh0 = (const float*)d_in[10];
    const float* dbih0 = (const float*)d_in[11];
    const float* dbhh0 = (const float*)d_in[12];
    const float* dWih1 = (const float*)d_in[13];
    const float* dWhh1 = (const float*)d_in[14];
    const float* dbih1 = (const float*)d_in[15];
    const float* dbhh1 = (const float*)d_in[16];
    const float* linW  = (const float*)d_in[17];
    const float* linb  = (const float*)d_in[18];

    float* ws = (float*)d_ws;
    int* bar = (int*)(ws + WS_BAR);

    hipMemsetAsync(bar, 0, 2048, stream);

    hipLaunchKernelGGL(lstm_persist, dim3(NWG), dim3(256), 0, stream,
                       x, eWih0, eWhh0, ebih0, ebhh0, eWih1, eWhh1, ebih1, ebhh1,
                       dWih0, dWhh0, dbih0, dbhh0, dWih1, dWhh1, dbih1, dbhh1,
                       linW, linb, (float*)d_out, ws, bar);
}

// Round 4
// 44384.836 us; speedup vs baseline: 2.3671x; 1.1211x over previous
//
#include <hip/hip_runtime.h>
#include <math.h>

#define T_ 256
#define H_ 512
#define NWG 256

typedef short bf16x8 __attribute__((ext_vector_type(8)));
typedef float f32x4 __attribute__((ext_vector_type(4)));

// ---------- ws byte offsets ----------
#define O_H0HI 0u          // 2 bufs x 128x512 bf16 = 262144 B
#define O_H0LO 262144u
#define O_H1HI 524288u
#define O_H1LO 786432u
#define O_C0   1048576u    // 128x512 f32
#define O_C1   1310720u
#define O_XIN0 1572864u    // [u*4+g][b] f32 = 1 MB
#define O_PK   2621440u    // 5 packs x 2048 f32
#define O_FLAG 2793472u    // 256 flags x 64B

// ---------- LDS byte offsets (128 KB dynamic) ----------
#define E0HI 0u            // 16 rows x 576 bf16 (x|h0)
#define E0LO 18432u
#define E1HI 36864u        // 16 rows x 1024 bf16 (h0|h1)
#define E1LO 69632u
#define D0HI 0u            // 16 rows x 1024 (Weff|dWhh0)
#define D0LO 32768u
#define D1HI 65536u        // 16 rows x 1024 (dWih1|dWhh1)
#define D1LO 98304u

__device__ __forceinline__ float sigf(float x) { return 1.0f / (1.0f + expf(-x)); }

__device__ __forceinline__ unsigned short f2bf(float f) {   // RNE
    union { float f; unsigned u; } v; v.f = f;
    unsigned r = v.u + 0x7FFFu + ((v.u >> 16) & 1u);
    return (unsigned short)(r >> 16);
}
__device__ __forceinline__ float bf2f(unsigned short h) {
    union { unsigned u; float f; } v; v.u = ((unsigned)h) << 16;
    return v.f;
}

// flag-array grid barrier: WG w sets flags[w*16]=gen; thread t polls flags[t*16].
__device__ __forceinline__ void gbar(int* flags, int w, int gen) {
    __syncthreads();
    __threadfence();   // release prior global writes (device scope)
    if (threadIdx.x == 0)
        __hip_atomic_store(flags + w * 16, gen, __ATOMIC_RELAXED, __HIP_MEMORY_SCOPE_AGENT);
    while (__hip_atomic_load(flags + threadIdx.x * 16, __ATOMIC_RELAXED, __HIP_MEMORY_SCOPE_AGENT) < gen)
        __builtin_amdgcn_s_sleep(1);
    __threadfence();   // acquire
    __syncthreads();
}

// store one weight element as hi/lo bf16 into swizzled LDS planes
__device__ __forceinline__ void st_w(char* smem, unsigned hiB, unsigned loB, unsigned K2,
                                     unsigned m, unsigned k, float v) {
    unsigned short hh = f2bf(v);
    unsigned short ll = f2bf(v - bf2f(hh));
    unsigned off = (m * K2 + k * 2) ^ ((m & 7) << 4);
    *(unsigned short*)(smem + hiB + off) = hh;
    *(unsigned short*)(smem + loB + off) = ll;
}

// one K-segment: A (16 rows) from swizzled LDS hi/lo, B from global bf16 hi/lo [b][k].
// 3 MFMAs per 32-k step: hi*hi -> acc0 ; hi*lo + lo*hi -> acc1.
template <int NSTEP>
__device__ __forceinline__ void seg_mfma(
    const char* smem, unsigned hiB, unsigned loB, unsigned K2, unsigned wk0,
    const unsigned short* __restrict__ bh, const unsigned short* __restrict__ bl,
    unsigned act_base, int lane, f32x4& acc0, f32x4& acc1) {
    const unsigned m = lane & 15, q = lane >> 4;
    const unsigned swz = (m & 7) << 4;
    const unsigned wb = m * K2 + (wk0 + q * 8) * 2;
    const unsigned ab = act_base + q * 8;
    #pragma unroll
    for (int s = 0; s < NSTEP; ++s) {
        bf16x8 ahi = *(const bf16x8*)(smem + hiB + ((wb + s * 64) ^ swz));
        bf16x8 alo = *(const bf16x8*)(smem + loB + ((wb + s * 64) ^ swz));
        bf16x8 bhi = *(const bf16x8*)(bh + ab + s * 32);
        bf16x8 blo = *(const bf16x8*)(bl + ab + s * 32);
        acc0 = __builtin_amdgcn_mfma_f32_16x16x32_bf16(ahi, bhi, acc0, 0, 0, 0);
        acc1 = __builtin_amdgcn_mfma_f32_16x16x32_bf16(ahi, blo, acc1, 0, 0, 0);
        acc1 = __builtin_amdgcn_mfma_f32_16x16x32_bf16(alo, bhi, acc1, 0, 0, 0);
    }
}

// encoder cell-A x-segment (K=64): B built on the fly from fp32 x row
__device__ __forceinline__ void xseg_mfma(
    const char* smem, unsigned hiB, unsigned loB, unsigned K2,
    const float* __restrict__ xrow, int lane, f32x4& acc0, f32x4& acc1) {
    const unsigned m = lane & 15, q = lane >> 4;
    const unsigned swz = (m & 7) << 4;
    #pragma unroll
    for (int s = 0; s < 2; ++s) {
        unsigned kk = s * 32 + q * 8;
        bf16x8 ahi = *(const bf16x8*)(smem + hiB + ((m * K2 + kk * 2) ^ swz));
        bf16x8 alo = *(const bf16x8*)(smem + loB + ((m * K2 + kk * 2) ^ swz));
        float4 f0 = *(const float4*)(xrow + kk);
        float4 f1 = *(const float4*)(xrow + kk + 4);
        float fs[8] = { f0.x, f0.y, f0.z, f0.w, f1.x, f1.y, f1.z, f1.w };
        bf16x8 bhi, blo;
        #pragma unroll
        for (int j = 0; j < 8; ++j) {
            unsigned short hh = f2bf(fs[j]);
            bhi[j] = (short)hh;
            blo[j] = (short)f2bf(fs[j] - bf2f(hh));
        }
        acc0 = __builtin_amdgcn_mfma_f32_16x16x32_bf16(ahi, bhi, acc0, 0, 0, 0);
        acc1 = __builtin_amdgcn_mfma_f32_16x16x32_bf16(ahi, blo, acc1, 0, 0, 0);
        acc1 = __builtin_amdgcn_mfma_f32_16x16x32_bf16(alo, bhi, acc1, 0, 0, 0);
    }
}

// LSTM epilogue: lane owns 4 gate preacts of one (u,b)
__device__ __forceinline__ void epilogue(f32x4 acc, const float* pkb, int u, int b,
                                         float* cArr, unsigned short* hhi, unsigned short* hlo) {
    const float4 bz = *(const float4*)(pkb + (size_t)u * 4);
    float gi = sigf(acc[0] + bz.x);
    float gf = sigf(acc[1] + bz.y);
    float gt = tanhf(acc[2] + bz.z);
    float go = sigf(acc[3] + bz.w);
    const unsigned ci = (unsigned)b * H_ + u;
    float cn = gf * cArr[ci] + gi * gt;
    cArr[ci] = cn;
    float hv = go * tanhf(cn);
    unsigned short hh = f2bf(hv);
    hhi[ci] = hh;
    hlo[ci] = f2bf(hv - bf2f(hh));
}

// out(t) = h1 @ linW.T + linb, h1 reconstructed hi+lo; also used for final step
__device__ __forceinline__ void linear_out(const unsigned short* __restrict__ h1h,
                                           const unsigned short* __restrict__ h1l,
                                           const float* __restrict__ linW,
                                           const float* __restrict__ linb,
                                           float* __restrict__ out, int w, int tid, int t) {
    const int bl = w >> 1;
    const int kq = tid & 7;
    const int f = (w & 1) * 32 + (tid >> 3);
    const unsigned base = (unsigned)bl * H_ + kq * 64;
    const float4* wv = (const float4*)(linW + (size_t)f * H_ + kq * 64);
    float s = 0.f;
    #pragma unroll
    for (int i4 = 0; i4 < 16; ++i4) {
        ushort4 hh = *(const ushort4*)(h1h + base + i4 * 4);
        ushort4 ll = *(const ushort4*)(h1l + base + i4 * 4);
        float4 wf = wv[i4];
        s += (bf2f(hh.x) + bf2f(ll.x)) * wf.x;
        s += (bf2f(hh.y) + bf2f(ll.y)) * wf.y;
        s += (bf2f(hh.z) + bf2f(ll.z)) * wf.z;
        s += (bf2f(hh.w) + bf2f(ll.w)) * wf.w;
    }
    s += __shfl_xor(s, 1);
    s += __shfl_xor(s, 2);
    s += __shfl_xor(s, 4);
    if (kq == 0)
        out[((size_t)bl * T_ + (255 - t)) * 64 + f] = s + linb[f];
}

__global__ __launch_bounds__(256, 1) void lstm_persist(
    const float* __restrict__ x,
    const float* __restrict__ eWih0, const float* __restrict__ eWhh0,
    const float* __restrict__ ebih0, const float* __restrict__ ebhh0,
    const float* __restrict__ eWih1, const float* __restrict__ eWhh1,
    const float* __restrict__ ebih1, const float* __restrict__ ebhh1,
    const float* __restrict__ dWih0, const float* __restrict__ dWhh0,
    const float* __restrict__ dbih0, const float* __restrict__ dbhh0,
    const float* __restrict__ dWih1, const float* __restrict__ dWhh1,
    const float* __restrict__ dbih1, const float* __restrict__ dbhh1,
    const float* __restrict__ linW,  const float* __restrict__ linb,
    float* __restrict__ out, char* __restrict__ wsb, int* __restrict__ flags) {
    extern __shared__ char smem[];
    const int w = blockIdx.x, tid = threadIdx.x;
    const int lane = tid & 63, wave = tid >> 6;
    const int gid = w * 256 + tid;

    // wave -> output tile: 16 rows (4 u x 4 gates interleaved) x 16 b
    const int r_tile = w >> 1;
    const int c_tile = (w & 1) * 4 + wave;
    const int u_base = r_tile * 4;
    const int u = u_base + (lane >> 4);       // C/D row group = this lane's u
    const int b = c_tile * 16 + (lane & 15);  // C/D col = this lane's batch

    unsigned short* h0hi[2] = { (unsigned short*)(wsb + O_H0HI), (unsigned short*)(wsb + O_H0HI + 131072u) };
    unsigned short* h0lo[2] = { (unsigned short*)(wsb + O_H0LO), (unsigned short*)(wsb + O_H0LO + 131072u) };
    unsigned short* h1hi[2] = { (unsigned short*)(wsb + O_H1HI), (unsigned short*)(wsb + O_H1HI + 131072u) };
    unsigned short* h1lo[2] = { (unsigned short*)(wsb + O_H1LO), (unsigned short*)(wsb + O_H1LO + 131072u) };
    float* c0 = (float*)(wsb + O_C0);
    float* c1 = (float*)(wsb + O_C1);
    float* xin0p = (float*)(wsb + O_XIN0);
    float* pk = (float*)(wsb + O_PK);
    int gen = 0;

    // ================= INIT =================
    h0hi[1][gid] = 0; h0lo[1][gid] = 0; h1hi[1][gid] = 0; h1lo[1][gid] = 0;
    c0[gid] = 0.f; c1[gid] = 0.f;

    if (gid < 10240) {   // bias packs [u*4+g], 5 packs
        int p = gid >> 11, r = gid & 2047;
        int uu = r >> 2, g = r & 3, gr = g * H_ + uu;
        float v;
        if (p == 0)      v = ebih0[gr] + ebhh0[gr];
        else if (p == 1) v = ebih1[gr] + ebhh1[gr];
        else if (p == 2) v = dbih0[gr] + dbhh0[gr];
        else if (p == 3) {
            v = dbih0[gr] + dbhh0[gr];
            float s = 0.f;
            for (int f = 0; f < 64; ++f) s += dWih0[(size_t)gr * 64 + f] * linb[f];
            v += s;
        } else           v = dbih1[gr] + dbhh1[gr];
        pk[gid] = v;
    }
    // xin0p[(u*4+g)*128+b] = dot(dWih0[g*512+u], x[b][255])
    for (int e = gid; e < 262144; e += 65536) {
        int r = e >> 7, bb = e & 127;
        int uu = r >> 2, g = r & 3, gr = g * H_ + uu;
        const float* xr = x + ((size_t)bb * T_ + (T_ - 1)) * 64;
        const float* wr = dWih0 + (size_t)gr * 64;
        float s = 0.f;
        for (int f = 0; f < 64; ++f) s += wr[f] * xr[f];
        xin0p[e] = s;
    }
    // encoder weights -> swizzled LDS hi/lo
    for (int m = 0; m < 16; ++m) {
        const int gr = (m & 3) * H_ + u_base + (m >> 2);
        for (int k = tid; k < 576; k += 256) {
            float v = (k < 64) ? eWih0[(size_t)gr * 64 + k] : eWhh0[(size_t)gr * H_ + (k - 64)];
            st_w(smem, E0HI, E0LO, 1152, m, k, v);
        }
        for (int k = tid; k < 1024; k += 256) {
            float v = (k < 512) ? eWih1[(size_t)gr * H_ + k] : eWhh1[(size_t)gr * H_ + (k - 512)];
            st_w(smem, E1HI, E1LO, 2048, m, k, v);
        }
    }
    gbar(flags, w, ++gen);

    // ================= ENCODER =================
    for (int t = 0; t < T_; ++t) {
        const unsigned cp = t & 1, pp = (t + 1) & 1;
        {   // cell A: [x_t | h0_{t-1}]
            f32x4 acc0 = { 0, 0, 0, 0 }, acc1 = { 0, 0, 0, 0 };
            const float* xrow = x + ((size_t)b * T_ + t) * 64;
            xseg_mfma(smem, E0HI, E0LO, 1152, xrow, lane, acc0, acc1);
            seg_mfma<16>(smem, E0HI, E0LO, 1152, 64, h0hi[pp], h0lo[pp], (unsigned)b * H_, lane, acc0, acc1);
            epilogue(acc0 + acc1, pk, u, b, c0, h0hi[cp], h0lo[cp]);
        }
        gbar(flags, w, ++gen);
        {   // cell B: [h0_t | h1_{t-1}]
            f32x4 acc0 = { 0, 0, 0, 0 }, acc1 = { 0, 0, 0, 0 };
            seg_mfma<16>(smem, E1HI, E1LO, 2048, 0,   h0hi[cp], h0lo[cp], (unsigned)b * H_, lane, acc0, acc1);
            seg_mfma<16>(smem, E1HI, E1LO, 2048, 512, h1hi[pp], h1lo[pp], (unsigned)b * H_, lane, acc0, acc1);
            epilogue(acc0 + acc1, pk + 2048, u, b, c1, h1hi[cp], h1lo[cp]);
        }
        gbar(flags, w, ++gen);
    }

    // ================= TRANSITION: decoder weights -> LDS (LDS is WG-private) =================
    __syncthreads();
    for (int m = 0; m < 16; ++m) {
        const int gr = (m & 3) * H_ + u_base + (m >> 2);
        const float* wr = dWih0 + (size_t)gr * 64;
        for (int k = tid; k < 1024; k += 256) {
            float v;
            if (k < 512) {   // Weff = dWih0 @ linW
                float s = 0.f;
                for (int f = 0; f < 64; ++f) s += wr[f] * linW[(size_t)f * H_ + k];
                v = s;
            } else v = dWhh0[(size_t)gr * H_ + (k - 512)];
            st_w(smem, D0HI, D0LO, 2048, m, k, v);
            float v1 = (k < 512) ? dWih1[(size_t)gr * H_ + k] : dWhh1[(size_t)gr * H_ + (k - 512)];
            st_w(smem, D1HI, D1LO, 2048, m, k, v1);
        }
    }
    __syncthreads();

    // ================= DECODER =================
    for (int t = 0; t < T_; ++t) {
        const unsigned cp = t & 1, pp = (t + 1) & 1;
        {   // dec0: Weff.h1_{t-1} (or xin0 at t=0) + dWhh0.h0_{t-1}; fold linear(t-1)
            f32x4 acc0 = { 0, 0, 0, 0 }, acc1 = { 0, 0, 0, 0 };
            if (t > 0)
                seg_mfma<16>(smem, D0HI, D0LO, 2048, 0, h1hi[pp], h1lo[pp], (unsigned)b * H_, lane, acc0, acc1);
            seg_mfma<16>(smem, D0HI, D0LO, 2048, 512, h0hi[pp], h0lo[pp], (unsigned)b * H_, lane, acc0, acc1);
            f32x4 acc = acc0 + acc1;
            if (t == 0) {
                #pragma unroll
                for (int j = 0; j < 4; ++j) acc[j] += xin0p[(size_t)(u * 4 + j) * 128 + b];
            }
            epilogue(acc, pk + (t > 0 ? 6144 : 4096), u, b, c0, h0hi[cp], h0lo[cp]);
            if (t > 0) linear_out(h1hi[pp], h1lo[pp], linW, linb, out, w, tid, t - 1);
        }
        gbar(flags, w, ++gen);
        {   // dec1: dWih1.h0_t + dWhh1.h1_{t-1}
            f32x4 acc0 = { 0, 0, 0, 0 }, acc1 = { 0, 0, 0, 0 };
            seg_mfma<16>(smem, D1HI, D1LO, 2048, 0,   h0hi[cp], h0lo[cp], (unsigned)b * H_, lane, acc0, acc1);
            seg_mfma<16>(smem, D1HI, D1LO, 2048, 512, h1hi[pp], h1lo[pp], (unsigned)b * H_, lane, acc0, acc1);
            epilogue(acc0 + acc1, pk + 8192, u, b, c1, h1hi[cp], h1lo[cp]);
        }
        gbar(flags, w, ++gen);
    }
    // final output (t=255): h1_255 lives in parity buf 1
    linear_out(h1hi[1], h1lo[1], linW, linb, out, w, tid, 255);
}

extern "C" void kernel_launch(void* const* d_in, const int* in_sizes, int n_in,
                              void* d_out, int out_size, void* d_ws, size_t ws_size,
                              hipStream_t stream) {
    (void)in_sizes; (void)n_in; (void)out_size; (void)ws_size;
    const float* x     = (const float*)d_in[0];
    const float* eWih0 = (const float*)d_in[1];
    const float* eWhh0 = (const float*)d_in[2];
    const float* ebih0 = (const float*)d_in[3];
    const float* ebhh0 = (const float*)d_in[4];
    const float* eWih1 = (const float*)d_in[5];
    const float* eWhh1 = (const float*)d_in[6];
    const float* ebih1 = (const float*)d_in[7];
    const float* ebhh1 = (const float*)d_in[8];
    const float* dWih0 = (const float*)d_in[9];
    const float* dWhh0 = (const float*)d_in[10];
    const float* dbih0 = (const float*)d_in[11];
    const float* dbhh0 = (const float*)d_in[12];
    const float* dWih1 = (const float*)d_in[13];
    const float* dWhh1 = (const float*)d_in[14];
    const float* dbih1 = (const float*)d_in[15];
    const float* dbhh1 = (const float*)d_in[16];
    const float* linW  = (const float*)d_in[17];
    const float* linb  = (const float*)d_in[18];

    char* wsb  = (char*)d_ws;
    int* flags = (int*)(wsb + O_FLAG);

    static const int lds_bytes = 131072;
    hipFuncSetAttribute((const void*)lstm_persist,
                        hipFuncAttributeMaxDynamicSharedMemorySize, lds_bytes);

    hipMemsetAsync(flags, 0, 16384, stream);

    hipLaunchKernelGGL(lstm_persist, dim3(NWG), dim3(256), lds_bytes, stream,
                       x, eWih0, eWhh0, ebih0, ebhh0, eWih1, eWhh1, ebih1, ebhh1,
                       dWih0, dWhh0, dbih0, dbhh0, dWih1, dWhh1, dbih1, dbhh1,
                       linW, linb, (float*)d_out, wsb, flags);
}